// Round 4
// baseline (87.873 us; speedup 1.0000x reference)
//
#include <hip/hip_runtime.h>

// PatchManifoldLossPre: resize (8,19,512,512) -> (8,19,48,48) with jax.image.resize
// bilinear (antialias=True, triangle kernel, half-pixel centers), split into 4x4
// patches of 12x12, P[16, 21888], value = mean(weights * pairwise-MSD(P)).
// pairwise-MSD via Gram: map[a,b] = (G[aa]+G[bb]-2G[ab])/N.
//
// Round-4 structure: k_init (zero G/tickets) + ONE fused kernel, 608 blocks x 128.
//  - Vertical pass STREAMS the ~139-input-row span once per block (amp 1.09x vs
//    2.06x for the round-2/3 per-output gather): 12 float4 register accumulators,
//    per-input-row 12-weight LDS table read as 3x ds_read_b128 broadcast.
//  - Horizontal gather from swizzled LDS tile (c -> c + 4*(c>>5), stride 580).
//  - Per-bc ticket: 4th-arriving group block computes that bc's Gram (atomicAdd
//    into G); global ticket: last bc computes the weighted scalar.

#define HIN 512
#define WOUT 48
#define NTAP 22
#define NBC 152          // 8*19
#define GRPV 12          // output rows per block (== patch size)
#define SPANMAX 140      // max input-row span (measured: 139)
#define TSTRIDE 580      // swizzled LDS row stride in floats
#define KS (512.0 / 48.0)

// Triangle-kernel resize weights matching jax.image.resize(method="bilinear",
// antialias=True): sample s=(i+0.5)*KS-0.5, kernel scale KS, normalize over valid
// taps. Window clamped into [0, HIN-NTAP]; clamped-in taps all have zero weight.
__device__ __forceinline__ int compute_weights(int i, float* w) {
  double s = (i + 0.5) * KS - 0.5;
  int stc = (int)ceil(s - KS);
  if (stc < 0) stc = 0;
  if (stc > HIN - NTAP) stc = HIN - NTAP;
  double wr[NTAP];
  double sum = 0.0;
#pragma unroll
  for (int k = 0; k < NTAP; ++k) {
    int j = stc + k;
    double d = fabs(s - (double)j) * (1.0 / KS);
    double wv = 1.0 - d;
    if (wv < 0.0) wv = 0.0;
    if (j >= HIN) wv = 0.0;  // j<0 impossible after clamp
    wr[k] = wv;
    sum += wv;
  }
  double inv = 1.0 / sum;
#pragma unroll
  for (int k = 0; k < NTAP; ++k) w[k] = (float)(wr[k] * inv);
  return stc;
}

__global__ __launch_bounds__(256) void k_init(float* __restrict__ G,
                                              unsigned* __restrict__ tickets) {
  const int t = threadIdx.x;
  G[t] = 0.f;
  if (t <= NBC) tickets[t] = 0u;  // 152 per-bc tickets + 1 global
}

__global__ __launch_bounds__(128) void k_fused(const float* __restrict__ pred,
                                               const float* __restrict__ wts,
                                               float* __restrict__ smallimg,
                                               float* __restrict__ G,
                                               unsigned* __restrict__ tickets,
                                               float* __restrict__ out) {
  __shared__ float hw[NTAP][WOUT];        // 4224 B
  __shared__ int hst[WOUT];
  __shared__ float wtab[SPANMAX][GRPV];   // 6720 B: input-row -> 12 out-row weights
  __shared__ float tile[GRPV * TSTRIDE];  // 27840 B (also reused by gram/final)
  __shared__ unsigned sticket;
  __shared__ float partial[2];

  const int t = threadIdx.x;
  const int bc = blockIdx.x >> 2;
  const int g = blockIdx.x & 3;
  const int oy0 = g * GRPV;

  if (t < WOUT) {
    float wr[NTAP];
    hst[t] = compute_weights(t, wr);
#pragma unroll
    for (int k = 0; k < NTAP; ++k) hw[k][t] = wr[k];
  }
  __syncthreads();

  const int lo = hst[oy0];
  const int span = hst[oy0 + GRPV - 1] + NTAP - lo;  // <= 139

  // Per-input-row weight table: wtab[row][r] = weight of input row lo+row in
  // output row oy0+r (zero outside the 22-tap window).
  for (int idx = t; idx < span * GRPV; idx += 128) {
    const int row = idx / GRPV;
    const int r = idx - row * GRPV;
    const int k = lo + row - hst[oy0 + r];
    wtab[row][r] = ((unsigned)k < NTAP) ? hw[k][oy0 + r] : 0.f;
  }
  __syncthreads();

  // ---- Vertical pass: stream the span once, accumulate 12 output rows ----
  const int x = t << 2;  // float4 column slice
  const float* p = pred + (size_t)bc * (HIN * HIN) + (size_t)lo * HIN + x;
  float4 acc[GRPV];
#pragma unroll
  for (int r = 0; r < GRPV; ++r) acc[r] = make_float4(0.f, 0.f, 0.f, 0.f);

#define FMA4(A, W, V)                                   \
  A.x = fmaf(W, V.x, A.x); A.y = fmaf(W, V.y, A.y);     \
  A.z = fmaf(W, V.z, A.z); A.w = fmaf(W, V.w, A.w)

#define VROW(ri, V)                                                          \
  {                                                                          \
    const float4* wq = reinterpret_cast<const float4*>(&wtab[ri][0]);        \
    const float4 w0 = wq[0], w1 = wq[1], w2 = wq[2];                         \
    FMA4(acc[0], w0.x, V);  FMA4(acc[1], w0.y, V);                           \
    FMA4(acc[2], w0.z, V);  FMA4(acc[3], w0.w, V);                           \
    FMA4(acc[4], w1.x, V);  FMA4(acc[5], w1.y, V);                           \
    FMA4(acc[6], w1.z, V);  FMA4(acc[7], w1.w, V);                           \
    FMA4(acc[8], w2.x, V);  FMA4(acc[9], w2.y, V);                           \
    FMA4(acc[10], w2.x, V); FMA4(acc[11], w2.w, V);                          \
  }
// NOTE: careful — see corrected macro below (w2.x twice would be a bug).
#undef VROW
#define VROW(ri, V)                                                          \
  {                                                                          \
    const float4* wq = reinterpret_cast<const float4*>(&wtab[ri][0]);        \
    const float4 w0 = wq[0], w1 = wq[1], w2 = wq[2];                         \
    FMA4(acc[0], w0.x, V);  FMA4(acc[1], w0.y, V);                           \
    FMA4(acc[2], w0.z, V);  FMA4(acc[3], w0.w, V);                           \
    FMA4(acc[4], w1.x, V);  FMA4(acc[5], w1.y, V);                           \
    FMA4(acc[6], w1.z, V);  FMA4(acc[7], w1.w, V);                           \
    FMA4(acc[8], w2.x, V);  FMA4(acc[9], w2.y, V);                           \
    FMA4(acc[10], w2.z, V); FMA4(acc[11], w2.w, V);                          \
  }

  int row = 0;
  for (; row + 4 <= span; row += 4) {
    const float4 v0 = *reinterpret_cast<const float4*>(p);
    const float4 v1 = *reinterpret_cast<const float4*>(p + HIN);
    const float4 v2 = *reinterpret_cast<const float4*>(p + 2 * HIN);
    const float4 v3 = *reinterpret_cast<const float4*>(p + 3 * HIN);
    p += 4 * HIN;
    VROW(row + 0, v0);
    VROW(row + 1, v1);
    VROW(row + 2, v2);
    VROW(row + 3, v3);
  }
  for (; row < span; ++row) {
    const float4 v0 = *reinterpret_cast<const float4*>(p);
    p += HIN;
    VROW(row, v0);
  }

  // Write swizzled tile for the horizontal gather.
  const int xph = x + ((x >> 5) << 2);
#pragma unroll
  for (int r = 0; r < GRPV; ++r)
    *reinterpret_cast<float4*>(&tile[r * TSTRIDE + xph]) = acc[r];
  __syncthreads();

  // ---- Horizontal gather -> smallimg (coalesced stores) ----
#pragma unroll
  for (int it = 0; it < 5; ++it) {
    const int item = it * 128 + t;
    if (item < GRPV * WOUT) {
      const int r = item / WOUT;
      const int j = item - r * WOUT;
      const int stc = hst[j];
      const int rb = r * TSTRIDE;
      float a = 0.f;
#pragma unroll
      for (int k = 0; k < NTAP; ++k) {
        const int cc = stc + k;
        a = fmaf(hw[k][j], tile[rb + cc + ((cc >> 5) << 2)], a);
      }
      smallimg[(size_t)bc * (WOUT * WOUT) + (oy0 + r) * WOUT + j] = a;
    }
  }

  // ---- Per-bc ticket: 4th arrival computes this bc's Gram ----
  __threadfence();
  __syncthreads();
  if (t == 0) sticket = atomicAdd(&tickets[bc], 1u);
  __syncthreads();
  if (sticket != 3u) return;

  __threadfence();       // acquire: other groups' smallimg writes
  float* gimg = tile;    // reuse LDS (2304 floats)
  const float* src = smallimg + (size_t)bc * (WOUT * WOUT);
  for (int idx = t; idx < (WOUT * WOUT) / 4; idx += 128) {
    reinterpret_cast<float4*>(gimg)[idx] = reinterpret_cast<const float4*>(src)[idx];
  }
  __syncthreads();
  float gacc[2];
#pragma unroll
  for (int i = 0; i < 2; ++i) {
    const int pp = t + 128 * i;
    const int a = pp >> 4, b = pp & 15;
    const float* pa = &gimg[((a >> 2) * GRPV) * WOUT + (a & 3) * GRPV];
    const float* pb = &gimg[((b >> 2) * GRPV) * WOUT + (b & 3) * GRPV];
    float s = 0.f;
    for (int y = 0; y < GRPV; ++y) {
#pragma unroll
      for (int q = 0; q < 3; ++q) {
        const float4 va = *reinterpret_cast<const float4*>(pa + y * WOUT + q * 4);
        const float4 vb = *reinterpret_cast<const float4*>(pb + y * WOUT + q * 4);
        s += va.x * vb.x + va.y * vb.y + va.z * vb.z + va.w * vb.w;
      }
    }
    gacc[i] = s;
  }
  atomicAdd(&G[t], gacc[0]);
  atomicAdd(&G[t + 128], gacc[1]);

  // ---- Global ticket: last bc computes the final scalar ----
  __threadfence();
  __syncthreads();
  if (t == 0) sticket = atomicAdd(&tickets[NBC], 1u);
  __syncthreads();
  if (sticket != NBC - 1) return;

  __threadfence();
  float* Gs = tile;  // safe: all gimg reads completed before the ticket barrier
  Gs[t] = atomicAdd(&G[t], 0.f);            // coherent device-scope readback
  Gs[t + 128] = atomicAdd(&G[t + 128], 0.f);
  __syncthreads();
  float v = 0.f;
#pragma unroll
  for (int i = 0; i < 2; ++i) {
    const int pp = t + 128 * i;
    const int a = pp >> 4, b = pp & 15;
    v += wts[pp] * (Gs[a * 17] + Gs[b * 17] - 2.f * Gs[pp]);
  }
#pragma unroll
  for (int off = 32; off > 0; off >>= 1) v += __shfl_down(v, off, 64);
  if ((t & 63) == 0) partial[t >> 6] = v;
  __syncthreads();
  if (t == 0) out[0] = (partial[0] + partial[1]) * (float)(1.0 / (256.0 * 21888.0));
}

extern "C" void kernel_launch(void* const* d_in, const int* in_sizes, int n_in,
                              void* d_out, int out_size, void* d_ws, size_t ws_size,
                              hipStream_t stream) {
  const float* pred = (const float*)d_in[0];
  const float* wts = (const float*)d_in[1];
  float* out = (float*)d_out;
  float* G = (float*)d_ws;                              // 256 floats
  unsigned* tickets = (unsigned*)((char*)d_ws + 1024);  // 153 u32
  float* smallimg = (float*)((char*)d_ws + 2048);       // 152*48*48 floats

  hipLaunchKernelGGL(k_init, dim3(1), dim3(256), 0, stream, G, tickets);
  hipLaunchKernelGGL(k_fused, dim3(NBC * 4), dim3(128), 0, stream,
                     pred, wts, smallimg, G, tickets, out);
}

// Round 5
// 43.193 us; speedup vs baseline: 2.0344x; 2.0344x over previous
//
#include <hip/hip_runtime.h>

// PatchManifoldLossPre: resize (8,19,512,512) -> (8,19,48,48) with jax.image.resize
// bilinear (antialias=True, triangle kernel, half-pixel centers), split into 4x4
// patches of 12x12, P[16, 21888], value = mean(weights * pairwise-MSD(P)).
// pairwise-MSD via Gram: map[a,b] = (G[aa]+G[bb]-2G[ab])/N.
//
// Round-5: the machine is latency-bound, not traffic-bound (round-4 lesson:
// amp-1.09 streaming @ 8.9% occupancy = 140us; redundant-load gather @ high
// occupancy wins). Structure:
//  k_resize     — 3648 blocks (152 bc x 24 row-pairs) x 256 thr. Thread = one
//                 output row x one float4 column slice: 22 independent coalesced
//                 loads + 88 FMA, single float4 acc (low VGPR). Horizontal gather
//                 via swizzled LDS tile (c -> c + 4*(c>>5), ~2-way = free).
//                 XCD-chunked block remap for tap-overlap L2 reuse.
//                 Block 0 zeroes G + ticket (no memset dispatch).
//  k_gram_final — 152 blocks; per-bc Gram -> G atomics; last block (device
//                 ticket) computes the weighted scalar (round-3 validated).

#define HIN 512
#define WOUT 48
#define NTAP 22
#define NBC 152          // 8*19
#define NPAIR 24         // row-pairs per bc
#define NBLK (NBC * NPAIR)   // 3648 = 8 * 456
#define TSTRIDE 580      // swizzled LDS row stride in floats
#define GROUP 12         // patch size
#define KS (512.0 / 48.0)

// Triangle-kernel resize weights matching jax.image.resize(method="bilinear",
// antialias=True): sample s=(i+0.5)*KS-0.5, kernel scale KS, normalize over valid
// taps. Window clamped into [0, HIN-NTAP]; clamped-in taps all have zero weight.
__device__ __forceinline__ int compute_weights(int i, float* w) {
  double s = (i + 0.5) * KS - 0.5;
  int stc = (int)ceil(s - KS);
  if (stc < 0) stc = 0;
  if (stc > HIN - NTAP) stc = HIN - NTAP;
  double wr[NTAP];
  double sum = 0.0;
#pragma unroll
  for (int k = 0; k < NTAP; ++k) {
    int j = stc + k;
    double d = fabs(s - (double)j) * (1.0 / KS);
    double wv = 1.0 - d;
    if (wv < 0.0) wv = 0.0;
    if (j >= HIN) wv = 0.0;  // j<0 impossible after clamp
    wr[k] = wv;
    sum += wv;
  }
  double inv = 1.0 / sum;
#pragma unroll
  for (int k = 0; k < NTAP; ++k) w[k] = (float)(wr[k] * inv);
  return stc;
}

__global__ __launch_bounds__(256, 6) void k_resize(const float* __restrict__ pred,
                                                   float* __restrict__ smallimg,
                                                   float* __restrict__ G,
                                                   unsigned* __restrict__ ticket) {
  __shared__ float hw[NTAP][WOUT];   // 4224 B
  __shared__ int hst[WOUT];
  __shared__ float tile[2][TSTRIDE]; // 4640 B, swizzled

  const int t = threadIdx.x;
  // XCD-chunked remap: under round-robin block->XCD, XCD k receives blockIdx
  // === k (mod 8); give it a contiguous work chunk so row-adjacent pairs (which
  // share ~11 of 22 tap rows) reuse that XCD's L2.
  const int wid = (blockIdx.x & 7) * (NBLK / 8) + (blockIdx.x >> 3);
  const int bc = wid / NPAIR;
  const int pair = wid - bc * NPAIR;

  // Replace the memset dispatch (validated round 3): visible at kernel boundary.
  if (blockIdx.x == 0) {
    G[t] = 0.f;
    if (t == 0) *ticket = 0u;
  }

  if (t < WOUT) {
    float wr[NTAP];
    hst[t] = compute_weights(t, wr);
#pragma unroll
    for (int k = 0; k < NTAP; ++k) hw[k][t] = wr[k];
  }
  __syncthreads();

  // ---- Vertical pass: thread = (output row slot, float4 column slice) ----
  const int slot = t >> 7;              // 0..1 (uniform per wave)
  const int oy = pair * 2 + slot;
  const int x = (t & 127) << 2;         // 0..508
  const int base = hst[oy];             // wave-uniform
  const float* p = pred + (size_t)bc * (HIN * HIN) + (size_t)base * HIN + x;
  float4 a = make_float4(0.f, 0.f, 0.f, 0.f);
#pragma unroll
  for (int k = 0; k < NTAP; ++k) {
    const float4 v = *reinterpret_cast<const float4*>(p + (size_t)k * HIN);
    const float wk = hw[k][oy];         // wave-uniform LDS broadcast
    a.x = fmaf(wk, v.x, a.x);
    a.y = fmaf(wk, v.y, a.y);
    a.z = fmaf(wk, v.z, a.z);
    a.w = fmaf(wk, v.w, a.w);
  }
  *reinterpret_cast<float4*>(&tile[slot][x + ((x >> 5) << 2)]) = a;
  __syncthreads();

  // ---- Horizontal gather (96 of 256 threads) -> smallimg ----
  if (t < 2 * WOUT) {
    const int r = (t >= WOUT) ? 1 : 0;
    const int j = t - r * WOUT;
    const int stc = hst[j];
    float acc = 0.f;
#pragma unroll
    for (int k = 0; k < NTAP; ++k) {
      const int cc = stc + k;
      acc = fmaf(hw[k][j], tile[r][cc + ((cc >> 5) << 2)], acc);
    }
    smallimg[(size_t)bc * (WOUT * WOUT) + (pair * 2 + r) * WOUT + j] = acc;
  }
}

// One block per (b,c): stage 48x48 image in LDS, thread owns pair (a,b), Gram via
// atomics into G; the LAST block (device-scope ticket) computes the final scalar.
__global__ __launch_bounds__(256) void k_gram_final(const float* __restrict__ smallimg,
                                                    const float* __restrict__ wts,
                                                    float* __restrict__ G,
                                                    unsigned* __restrict__ ticket,
                                                    float* __restrict__ out) {
  __shared__ float img[WOUT * WOUT];
  __shared__ float Gs[256];
  __shared__ float partial[4];
  __shared__ unsigned lastv;

  const int tid = threadIdx.x;
  const float* src = smallimg + (size_t)blockIdx.x * (WOUT * WOUT);
  for (int idx = tid; idx < (WOUT * WOUT) / 4; idx += 256) {
    *reinterpret_cast<float4*>(&img[idx * 4]) =
        *reinterpret_cast<const float4*>(src + idx * 4);
  }
  __syncthreads();
  const int a = tid >> 4;
  const int b = tid & 15;
  const float* pa = &img[((a >> 2) * GROUP) * WOUT + (a & 3) * GROUP];
  const float* pb = &img[((b >> 2) * GROUP) * WOUT + (b & 3) * GROUP];
  float acc = 0.f;
  for (int y = 0; y < GROUP; ++y) {
#pragma unroll
    for (int q = 0; q < 3; ++q) {
      const float4 va = *reinterpret_cast<const float4*>(pa + y * WOUT + q * 4);
      const float4 vb = *reinterpret_cast<const float4*>(pb + y * WOUT + q * 4);
      acc += va.x * vb.x + va.y * vb.y + va.z * vb.z + va.w * vb.w;
    }
  }
  atomicAdd(&G[tid], acc);
  __threadfence();   // release: G-atomics ordered before the ticket increment
  __syncthreads();   // all 256 lanes' atomics issued+fenced before tid 0 tickets
  if (tid == 0) lastv = atomicAdd(ticket, 1u);
  __syncthreads();
  if (lastv != NBC - 1) return;

  // Last block: coherent readback of G (device-scope atomic read), then reduce.
  __threadfence();
  Gs[tid] = atomicAdd(&G[tid], 0.f);
  __syncthreads();
  float v = wts[tid] * (Gs[a * 17] + Gs[b * 17] - 2.0f * Gs[tid]);
#pragma unroll
  for (int off = 32; off > 0; off >>= 1) v += __shfl_down(v, off, 64);
  if ((tid & 63) == 0) partial[tid >> 6] = v;
  __syncthreads();
  if (tid == 0) {
    out[0] = (partial[0] + partial[1] + partial[2] + partial[3]) *
             (float)(1.0 / (256.0 * 21888.0));
  }
}

extern "C" void kernel_launch(void* const* d_in, const int* in_sizes, int n_in,
                              void* d_out, int out_size, void* d_ws, size_t ws_size,
                              hipStream_t stream) {
  const float* pred = (const float*)d_in[0];
  const float* wts = (const float*)d_in[1];
  float* out = (float*)d_out;
  float* G = (float*)d_ws;                              // bytes [0, 1024)
  unsigned* ticket = (unsigned*)((char*)d_ws + 1024);   // bytes [1024, 1028)
  float* smallimg = (float*)((char*)d_ws + 2048);       // 152*48*48 floats

  hipLaunchKernelGGL(k_resize, dim3(NBLK), dim3(256), 0, stream,
                     pred, smallimg, G, ticket);
  hipLaunchKernelGGL(k_gram_final, dim3(NBC), dim3(256), 0, stream,
                     smallimg, wts, G, ticket, out);
}